// Round 1
// baseline (2713.727 us; speedup 1.0000x reference)
//
#include <hip/hip_runtime.h>

#define BATCH   4
#define NPTS    16384
#define NCH     32
#define NPOINT  1024
#define NSAMPLE 32

#define FPS_T 512
#define FPS_K 32   // NPTS / FPS_T

// ---------------------------------------------------------------------------
// Kernel 1: farthest point sampling. One block per batch; all coords + dists
// live in VGPRs. Exact-match arithmetic (contract off, first-occurrence ties).
// ---------------------------------------------------------------------------
__global__ __launch_bounds__(FPS_T) void fps_kernel(const float* __restrict__ xyz,
                                                    int* __restrict__ fps_idx)
{
    const int b = blockIdx.x;
    const int t = threadIdx.x;
    const float* base = xyz + (size_t)b * NPTS * 3;

    float px[FPS_K], py[FPS_K], pz[FPS_K], dist[FPS_K];
#pragma unroll
    for (int k = 0; k < FPS_K; ++k) {
        const float* q = base + (size_t)(t + k * FPS_T) * 3;
        px[k] = q[0]; py[k] = q[1]; pz[k] = q[2];
        dist[k] = 1e10f;
    }

    __shared__ float s_wv[FPS_T / 64];
    __shared__ int   s_wi[FPS_T / 64];
    __shared__ int   s_sel;

    if (t == 0) fps_idx[b * NPOINT] = 0;
    int curW = 0;

    for (int it = 1; it < NPOINT; ++it) {
        const float* cp = base + (size_t)curW * 3;
        float cx = cp[0], cy = cp[1], cz = cp[2];
        float bv = -1.0f;
        int   bi = 0;
        {
#pragma clang fp contract(off)
#pragma unroll
            for (int k = 0; k < FPS_K; ++k) {
                float dx = px[k] - cx;
                float dy = py[k] - cy;
                float dz = pz[k] - cz;
                float d  = dx * dx + dy * dy;
                d = d + dz * dz;
                float dk = fminf(dist[k], d);
                dist[k] = dk;
                // ascending global index with k -> strict '>' keeps first max
                if (dk > bv) { bv = dk; bi = t + k * FPS_T; }
            }
        }
        // wave-level argmax (tie -> smaller index)
#pragma unroll
        for (int m = 32; m >= 1; m >>= 1) {
            float ov = __shfl_xor(bv, m);
            int   oi = __shfl_xor(bi, m);
            if (ov > bv || (ov == bv && oi < bi)) { bv = ov; bi = oi; }
        }
        if ((t & 63) == 0) { s_wv[t >> 6] = bv; s_wi[t >> 6] = bi; }
        __syncthreads();
        if (t == 0) {
            float v = s_wv[0]; int i = s_wi[0];
#pragma unroll
            for (int w = 1; w < FPS_T / 64; ++w) {
                float vw = s_wv[w]; int iw = s_wi[w];
                if (vw > v || (vw == v && iw < i)) { v = vw; i = iw; }
            }
            s_sel = i;
            fps_idx[b * NPOINT + it] = i;
        }
        __syncthreads();
        curW = __builtin_amdgcn_readfirstlane(s_sel);
    }
}

// ---------------------------------------------------------------------------
// Kernel 2/4: ball query. One wave per center, scan points in index order,
// collect first NSAMPLE within radius, pad with first hit (or 0). Early exit.
// cidx != nullptr -> centers gathered from xyz via cidx; else centers array.
// ---------------------------------------------------------------------------
__global__ __launch_bounds__(256) void ballq_kernel(const float* __restrict__ xyz,
                                                    const int* __restrict__ cidx,
                                                    const float* __restrict__ centers,
                                                    int* __restrict__ out_idx)
{
    const int lane = threadIdx.x & 63;
    const int cid  = blockIdx.x * 4 + (threadIdx.x >> 6);
    const int b    = cid >> 10;
    const float* base = xyz + (size_t)b * NPTS * 3;

    float cx, cy, cz;
    if (cidx) {
        int pi = cidx[cid];
        const float* p = base + (size_t)pi * 3;
        cx = p[0]; cy = p[1]; cz = p[2];
    } else {
        const float* p = centers + (size_t)cid * 3;
        cx = p[0]; cy = p[1]; cz = p[2];
    }

    const float R2 = (float)(0.8 * 0.8);
    int found = 0, firstp = 0;
    int* dst = out_idx + (size_t)cid * NSAMPLE;

    for (int chunk = 0; chunk < NPTS / 64; ++chunk) {
        int p = chunk * 64 + lane;
        const float* q = base + (size_t)p * 3;
        bool hit;
        {
#pragma clang fp contract(off)
            float dx = cx - q[0];
            float dy = cy - q[1];
            float dz = cz - q[2];
            float d2 = dx * dx + dy * dy;
            d2 = d2 + dz * dz;
            hit = d2 < R2;
        }
        unsigned long long m = __ballot(hit);
        if (m) {
            if (found == 0) firstp = chunk * 64 + __builtin_ctzll(m);
            int pos = found + __popcll(m & ((1ull << lane) - 1ull));
            if (hit && pos < NSAMPLE) dst[pos] = p;
            found += __popcll(m);
            if (found >= NSAMPLE) break;
        }
    }
    if (found < NSAMPLE) {
        int pad = (found == 0) ? 0 : firstp;
        int j = found + lane;
        if (j < NSAMPLE) dst[j] = pad;
    }
}

// ---------------------------------------------------------------------------
// Kernel 3: grouping + offset MLP (16ch -> 3ch) + mean(st*gxyz) -> mod_xyz,
// clipped copy -> output 0. Thread = (center, sample).
// ---------------------------------------------------------------------------
__global__ __launch_bounds__(256) void offset_kernel(const float* __restrict__ xyz,
                                                     const float* __restrict__ features,
                                                     const int* __restrict__ fps_idx,
                                                     const int* __restrict__ idx_a,
                                                     const float* __restrict__ w0,
                                                     const float* __restrict__ b0,
                                                     const float* __restrict__ w1,
                                                     const float* __restrict__ b1,
                                                     float* __restrict__ out0,
                                                     float* __restrict__ mod_xyz)
{
    const int t   = threadIdx.x;
    const int s   = t & 31;
    const int cid = blockIdx.x * 8 + (t >> 5);
    const int b   = cid >> 10;
    const float* base = xyz + (size_t)b * NPTS * 3;

    int pc = fps_idx[cid];
    const float* cp = base + (size_t)pc * 3;
    float nx = cp[0], ny = cp[1], nz = cp[2];

    int id = idx_a[(size_t)cid * NSAMPLE + s];
    const float* pp = base + (size_t)id * 3;

    float in[3 + NCH];
    in[0] = pp[0] - nx; in[1] = pp[1] - ny; in[2] = pp[2] - nz;
    const float4* fp = reinterpret_cast<const float4*>(features + ((size_t)b * NPTS + id) * NCH);
#pragma unroll
    for (int j = 0; j < NCH / 4; ++j) {
        float4 v = fp[j];
        in[3 + j * 4 + 0] = v.x; in[3 + j * 4 + 1] = v.y;
        in[3 + j * 4 + 2] = v.z; in[3 + j * 4 + 3] = v.w;
    }

    float h[16];
#pragma unroll
    for (int o = 0; o < 16; ++o) {
        float acc = b0[o];
#pragma unroll
        for (int c = 0; c < 35; ++c) acc = fmaf(w0[o * 35 + c], in[c], acc);
        h[o] = fmaxf(acc, 0.0f);
    }
    float st[3];
#pragma unroll
    for (int o = 0; o < 3; ++o) {
        float acc = b1[o];
#pragma unroll
        for (int c = 0; c < 16; ++c) acc = fmaf(w1[o * 16 + c], h[c], acc);
        st[o] = acc;
    }

    float sx = st[0] * in[0];
    float sy = st[1] * in[1];
    float sz = st[2] * in[2];
#pragma unroll
    for (int m = 16; m >= 1; m >>= 1) {
        sx += __shfl_xor(sx, m);
        sy += __shfl_xor(sy, m);
        sz += __shfl_xor(sz, m);
    }
    if (s == 0) {
        float mx = nx + sx * (1.0f / 32.0f);
        float my = ny + sy * (1.0f / 32.0f);
        float mz = nz + sz * (1.0f / 32.0f);
        mod_xyz[cid * 3 + 0] = mx;
        mod_xyz[cid * 3 + 1] = my;
        mod_xyz[cid * 3 + 2] = mz;
        out0[cid * 3 + 0] = fminf(fmaxf(mx, -2.0f), 2.0f);
        out0[cid * 3 + 1] = fminf(fmaxf(my, -2.0f), 2.0f);
        out0[cid * 3 + 2] = fminf(fmaxf(mz, -2.0f), 2.0f);
    }
}

// ---------------------------------------------------------------------------
// Kernel 5: grouping (mod_xyz, idx_g) + MLP 35->64->64->128 + max over samples.
// Output-channel loops stay rolled (uniform weight rows -> s_load + v_fmac);
// activations round-trip through per-thread LDS columns (conflict-free) so no
// runtime-indexed register arrays (which would spill to scratch).
// ---------------------------------------------------------------------------
__global__ __launch_bounds__(256) void final_kernel(const float* __restrict__ xyz,
                                                    const float* __restrict__ features,
                                                    const float* __restrict__ mod_xyz,
                                                    const int* __restrict__ idx_g,
                                                    const float* __restrict__ w0,
                                                    const float* __restrict__ b0,
                                                    const float* __restrict__ w1,
                                                    const float* __restrict__ b1,
                                                    const float* __restrict__ w2,
                                                    const float* __restrict__ b2,
                                                    float* __restrict__ out1)
{
    __shared__ float sbuf[64 * 256];
    const int t   = threadIdx.x;
    const int s   = t & 31;
    const int cid = blockIdx.x * 8 + (t >> 5);
    const int b   = cid >> 10;
    const int c   = cid & (NPOINT - 1);
    const float* base = xyz + (size_t)b * NPTS * 3;

    float nx = mod_xyz[cid * 3 + 0];
    float ny = mod_xyz[cid * 3 + 1];
    float nz = mod_xyz[cid * 3 + 2];
    int id = idx_g[(size_t)cid * NSAMPLE + s];
    const float* pp = base + (size_t)id * 3;

    float in[35];
    in[0] = pp[0] - nx; in[1] = pp[1] - ny; in[2] = pp[2] - nz;
    const float4* fp = reinterpret_cast<const float4*>(features + ((size_t)b * NPTS + id) * NCH);
#pragma unroll
    for (int j = 0; j < 8; ++j) {
        float4 v = fp[j];
        in[3 + j * 4 + 0] = v.x; in[3 + j * 4 + 1] = v.y;
        in[3 + j * 4 + 2] = v.z; in[3 + j * 4 + 3] = v.w;
    }

#pragma clang loop unroll(disable)
    for (int o = 0; o < 64; ++o) {
        float acc = b0[o];
#pragma unroll
        for (int cc = 0; cc < 35; ++cc) acc = fmaf(w0[o * 35 + cc], in[cc], acc);
        sbuf[o * 256 + t] = fmaxf(acc, 0.0f);
    }
    float g[64];
#pragma unroll
    for (int cc = 0; cc < 64; ++cc) g[cc] = sbuf[cc * 256 + t];

#pragma clang loop unroll(disable)
    for (int o = 0; o < 64; ++o) {
        float acc = b1[o];
#pragma unroll
        for (int cc = 0; cc < 64; ++cc) acc = fmaf(w1[o * 64 + cc], g[cc], acc);
        sbuf[o * 256 + t] = fmaxf(acc, 0.0f);
    }
    float h2[64];
#pragma unroll
    for (int cc = 0; cc < 64; ++cc) h2[cc] = sbuf[cc * 256 + t];

#pragma clang loop unroll(disable)
    for (int o = 0; o < 128; ++o) {
        float acc = b2[o];
#pragma unroll
        for (int cc = 0; cc < 64; ++cc) acc = fmaf(w2[o * 64 + cc], h2[cc], acc);
        acc = fmaxf(acc, 0.0f);
#pragma unroll
        for (int m = 16; m >= 1; m >>= 1) acc = fmaxf(acc, __shfl_xor(acc, m));
        if (s == 0) out1[((size_t)(b * 128 + o)) * NPOINT + c] = acc;
    }
}

// ---------------------------------------------------------------------------
extern "C" void kernel_launch(void* const* d_in, const int* in_sizes, int n_in,
                              void* d_out, int out_size, void* d_ws, size_t ws_size,
                              hipStream_t stream)
{
    (void)in_sizes; (void)n_in; (void)out_size; (void)ws_size;

    const float* xyz      = (const float*)d_in[0];
    const float* features = (const float*)d_in[1];
    const float* w_off0   = (const float*)d_in[2];
    const float* b_off0   = (const float*)d_in[3];
    const float* w_off1   = (const float*)d_in[4];
    const float* b_off1   = (const float*)d_in[5];
    const float* w0       = (const float*)d_in[6];
    const float* b0       = (const float*)d_in[7];
    const float* w1       = (const float*)d_in[8];
    const float* b1       = (const float*)d_in[9];
    const float* w2       = (const float*)d_in[10];
    const float* b2       = (const float*)d_in[11];

    char* ws = (char*)d_ws;
    int*   fps_idx = (int*)(ws);                 // 4096 ints      (16 KB)
    float* mod_xyz = (float*)(ws + 16384);       // 4096*3 floats  (48 KB)
    int*   idx_a   = (int*)(ws + 65536);         // 4096*32 ints   (512 KB)
    int*   idx_g   = (int*)(ws + 589824);        // 4096*32 ints   (512 KB)

    float* out0 = (float*)d_out;                            // (B,1024,3)
    float* out1 = (float*)d_out + (size_t)BATCH * NPOINT * 3; // (B,128,1024)

    hipLaunchKernelGGL(fps_kernel, dim3(BATCH), dim3(FPS_T), 0, stream,
                       xyz, fps_idx);
    hipLaunchKernelGGL(ballq_kernel, dim3(BATCH * NPOINT / 4), dim3(256), 0, stream,
                       xyz, fps_idx, (const float*)nullptr, idx_a);
    hipLaunchKernelGGL(offset_kernel, dim3(BATCH * NPOINT / 8), dim3(256), 0, stream,
                       xyz, features, fps_idx, idx_a, w_off0, b_off0, w_off1, b_off1,
                       out0, mod_xyz);
    hipLaunchKernelGGL(ballq_kernel, dim3(BATCH * NPOINT / 4), dim3(256), 0, stream,
                       xyz, (const int*)nullptr, mod_xyz, idx_g);
    hipLaunchKernelGGL(final_kernel, dim3(BATCH * NPOINT / 8), dim3(256), 0, stream,
                       xyz, features, mod_xyz, idx_g, w0, b0, w1, b1, w2, b2, out1);
}

// Round 5
// 2012.865 us; speedup vs baseline: 1.3482x; 1.3482x over previous
//
#include <hip/hip_runtime.h>

#define BATCH   4
#define NPTS    16384
#define NCH     32
#define NPOINT  1024
#define NSAMPLE 32

#define FPS_T 512
#define FPS_K 32            // NPTS / FPS_T
#define FPS_K2 (FPS_K / 2)  // float2-packed pairs

typedef float v2f __attribute__((ext_vector_type(2)));

// ---------------------------------------------------------------------------
// Kernel 1: farthest point sampling. One block per batch; all coords + dists
// live in VGPRs (launch_bounds(512,2) -> 256-VGPR budget, no spill).
// Packed float2 math (v_pk_*_f32, bit-identical to scalar), argmax carried as
// a packed double {hi=dist_bits, lo=~gidx} reduced with v_max_f64
// (first-occurrence tie-break preserved). One barrier per iteration via
// parity-buffered LDS; winner coords re-fetched through scalar cache.
// ---------------------------------------------------------------------------
__global__ __launch_bounds__(FPS_T, 2) void fps_kernel(const float* __restrict__ xyz,
                                                       int* __restrict__ fps_idx)
{
    const int b = blockIdx.x;
    const int t = threadIdx.x;
    const float* base = xyz + (size_t)b * NPTS * 3;

    v2f px[FPS_K2], py[FPS_K2], pz[FPS_K2], dist[FPS_K2];
    int nl[FPS_K];  // ~global_idx, packed-compare low words
#pragma unroll
    for (int k = 0; k < FPS_K2; ++k) {
        const float* q0 = base + (size_t)(t + (2 * k + 0) * FPS_T) * 3;
        const float* q1 = base + (size_t)(t + (2 * k + 1) * FPS_T) * 3;
        px[k] = (v2f){q0[0], q1[0]};
        py[k] = (v2f){q0[1], q1[1]};
        pz[k] = (v2f){q0[2], q1[2]};
        dist[k] = (v2f){1e10f, 1e10f};
        nl[2 * k + 0] = ~(t + (2 * k + 0) * FPS_T);
        nl[2 * k + 1] = ~(t + (2 * k + 1) * FPS_T);
    }

    __shared__ double s_red[2][FPS_T / 64];

    if (t == 0) fps_idx[b * NPOINT] = 0;
    float cx = base[0], cy = base[1], cz = base[2];

    for (int it = 1; it < NPOINT; ++it) {
        float bv = -1.0f;
        int   bl = 0;
        {
#pragma clang fp contract(off)
            v2f cxv = (v2f){cx, cx};
            v2f cyv = (v2f){cy, cy};
            v2f czv = (v2f){cz, cz};
#pragma unroll
            for (int k = 0; k < FPS_K2; ++k) {
                v2f dx = px[k] - cxv;
                v2f dy = py[k] - cyv;
                v2f dz = pz[k] - czv;
                v2f d  = dx * dx + dy * dy;
                d = d + dz * dz;
                v2f m = __builtin_elementwise_min(dist[k], d);
                dist[k] = m;
                // ascending global index order; strict '>' keeps first max
                if (m.x > bv) { bv = m.x; bl = nl[2 * k + 0]; }
                if (m.y > bv) { bv = m.y; bl = nl[2 * k + 1]; }
            }
        }
        // packed argmax candidate: positive-double bit order == (dist, ~idx)
        double best = __hiloint2double(__float_as_int(bv), bl);
#pragma unroll
        for (int m = 32; m >= 1; m >>= 1)
            best = fmax(best, __shfl_xor(best, m));
        if ((t & 63) == 0) s_red[it & 1][t >> 6] = best;
        __syncthreads();
        const double* r = s_red[it & 1];
        double w = fmax(fmax(fmax(r[0], r[1]), fmax(r[2], r[3])),
                        fmax(fmax(r[4], r[5]), fmax(r[6], r[7])));
        unsigned idx = ~(unsigned)__double2loint(w);
        if (t == 0) fps_idx[b * NPOINT + it] = (int)idx;
        unsigned idxu = __builtin_amdgcn_readfirstlane(idx);
        const float* cp = base + (size_t)idxu * 3;  // uniform -> scalar loads
        cx = cp[0]; cy = cp[1]; cz = cp[2];
    }
}

// ---------------------------------------------------------------------------
// Kernel 2/4: ball query. One wave per center, scan points in index order,
// collect first NSAMPLE within radius, pad with first hit (or 0). Early exit.
// cidx != nullptr -> centers gathered from xyz via cidx; else centers array.
// ---------------------------------------------------------------------------
__global__ __launch_bounds__(256) void ballq_kernel(const float* __restrict__ xyz,
                                                    const int* __restrict__ cidx,
                                                    const float* __restrict__ centers,
                                                    int* __restrict__ out_idx)
{
    const int lane = threadIdx.x & 63;
    const int cid  = blockIdx.x * 4 + (threadIdx.x >> 6);
    const int b    = cid >> 10;
    const float* base = xyz + (size_t)b * NPTS * 3;

    float cx, cy, cz;
    if (cidx) {
        int pi = cidx[cid];
        const float* p = base + (size_t)pi * 3;
        cx = p[0]; cy = p[1]; cz = p[2];
    } else {
        const float* p = centers + (size_t)cid * 3;
        cx = p[0]; cy = p[1]; cz = p[2];
    }

    const float R2 = (float)(0.8 * 0.8);
    int found = 0, firstp = 0;
    int* dst = out_idx + (size_t)cid * NSAMPLE;

    for (int chunk = 0; chunk < NPTS / 64; ++chunk) {
        int p = chunk * 64 + lane;
        const float* q = base + (size_t)p * 3;
        bool hit;
        {
#pragma clang fp contract(off)
            float dx = cx - q[0];
            float dy = cy - q[1];
            float dz = cz - q[2];
            float d2 = dx * dx + dy * dy;
            d2 = d2 + dz * dz;
            hit = d2 < R2;
        }
        unsigned long long m = __ballot(hit);
        if (m) {
            if (found == 0) firstp = chunk * 64 + __builtin_ctzll(m);
            int pos = found + __popcll(m & ((1ull << lane) - 1ull));
            if (hit && pos < NSAMPLE) dst[pos] = p;
            found += __popcll(m);
            if (found >= NSAMPLE) break;
        }
    }
    if (found < NSAMPLE) {
        int pad = (found == 0) ? 0 : firstp;
        int j = found + lane;
        if (j < NSAMPLE) dst[j] = pad;
    }
}

// ---------------------------------------------------------------------------
// Kernel 3: grouping + offset MLP (16ch -> 3ch) + mean(st*gxyz) -> mod_xyz,
// clipped copy -> output 0. Thread = (center, sample).
// ---------------------------------------------------------------------------
__global__ __launch_bounds__(256) void offset_kernel(const float* __restrict__ xyz,
                                                     const float* __restrict__ features,
                                                     const int* __restrict__ fps_idx,
                                                     const int* __restrict__ idx_a,
                                                     const float* __restrict__ w0,
                                                     const float* __restrict__ b0,
                                                     const float* __restrict__ w1,
                                                     const float* __restrict__ b1,
                                                     float* __restrict__ out0,
                                                     float* __restrict__ mod_xyz)
{
    const int t   = threadIdx.x;
    const int s   = t & 31;
    const int cid = blockIdx.x * 8 + (t >> 5);
    const int b   = cid >> 10;
    const float* base = xyz + (size_t)b * NPTS * 3;

    int pc = fps_idx[cid];
    const float* cp = base + (size_t)pc * 3;
    float nx = cp[0], ny = cp[1], nz = cp[2];

    int id = idx_a[(size_t)cid * NSAMPLE + s];
    const float* pp = base + (size_t)id * 3;

    float in[3 + NCH];
    in[0] = pp[0] - nx; in[1] = pp[1] - ny; in[2] = pp[2] - nz;
    const float4* fp = reinterpret_cast<const float4*>(features + ((size_t)b * NPTS + id) * NCH);
#pragma unroll
    for (int j = 0; j < NCH / 4; ++j) {
        float4 v = fp[j];
        in[3 + j * 4 + 0] = v.x; in[3 + j * 4 + 1] = v.y;
        in[3 + j * 4 + 2] = v.z; in[3 + j * 4 + 3] = v.w;
    }

    float h[16];
#pragma unroll
    for (int o = 0; o < 16; ++o) {
        float acc = b0[o];
#pragma unroll
        for (int c = 0; c < 35; ++c) acc = fmaf(w0[o * 35 + c], in[c], acc);
        h[o] = fmaxf(acc, 0.0f);
    }
    float st[3];
#pragma unroll
    for (int o = 0; o < 3; ++o) {
        float acc = b1[o];
#pragma unroll
        for (int c = 0; c < 16; ++c) acc = fmaf(w1[o * 16 + c], h[c], acc);
        st[o] = acc;
    }

    float sx = st[0] * in[0];
    float sy = st[1] * in[1];
    float sz = st[2] * in[2];
#pragma unroll
    for (int m = 16; m >= 1; m >>= 1) {
        sx += __shfl_xor(sx, m);
        sy += __shfl_xor(sy, m);
        sz += __shfl_xor(sz, m);
    }
    if (s == 0) {
        float mx = nx + sx * (1.0f / 32.0f);
        float my = ny + sy * (1.0f / 32.0f);
        float mz = nz + sz * (1.0f / 32.0f);
        mod_xyz[cid * 3 + 0] = mx;
        mod_xyz[cid * 3 + 1] = my;
        mod_xyz[cid * 3 + 2] = mz;
        out0[cid * 3 + 0] = fminf(fmaxf(mx, -2.0f), 2.0f);
        out0[cid * 3 + 1] = fminf(fmaxf(my, -2.0f), 2.0f);
        out0[cid * 3 + 2] = fminf(fmaxf(mz, -2.0f), 2.0f);
    }
}

// ---------------------------------------------------------------------------
// Kernel 5: grouping (mod_xyz, idx_g) + MLP 35->64->64->128 + max over samples.
// Output-channel loops stay rolled (uniform weight rows -> s_load + v_fmac);
// activations round-trip through per-thread LDS columns (conflict-free) so no
// runtime-indexed register arrays (which would spill to scratch).
// ---------------------------------------------------------------------------
__global__ __launch_bounds__(256) void final_kernel(const float* __restrict__ xyz,
                                                    const float* __restrict__ features,
                                                    const float* __restrict__ mod_xyz,
                                                    const int* __restrict__ idx_g,
                                                    const float* __restrict__ w0,
                                                    const float* __restrict__ b0,
                                                    const float* __restrict__ w1,
                                                    const float* __restrict__ b1,
                                                    const float* __restrict__ w2,
                                                    const float* __restrict__ b2,
                                                    float* __restrict__ out1)
{
    __shared__ float sbuf[64 * 256];
    const int t   = threadIdx.x;
    const int s   = t & 31;
    const int cid = blockIdx.x * 8 + (t >> 5);
    const int b   = cid >> 10;
    const int c   = cid & (NPOINT - 1);
    const float* base = xyz + (size_t)b * NPTS * 3;

    float nx = mod_xyz[cid * 3 + 0];
    float ny = mod_xyz[cid * 3 + 1];
    float nz = mod_xyz[cid * 3 + 2];
    int id = idx_g[(size_t)cid * NSAMPLE + s];
    const float* pp = base + (size_t)id * 3;

    float in[35];
    in[0] = pp[0] - nx; in[1] = pp[1] - ny; in[2] = pp[2] - nz;
    const float4* fp = reinterpret_cast<const float4*>(features + ((size_t)b * NPTS + id) * NCH);
#pragma unroll
    for (int j = 0; j < 8; ++j) {
        float4 v = fp[j];
        in[3 + j * 4 + 0] = v.x; in[3 + j * 4 + 1] = v.y;
        in[3 + j * 4 + 2] = v.z; in[3 + j * 4 + 3] = v.w;
    }

#pragma clang loop unroll(disable)
    for (int o = 0; o < 64; ++o) {
        float acc = b0[o];
#pragma unroll
        for (int cc = 0; cc < 35; ++cc) acc = fmaf(w0[o * 35 + cc], in[cc], acc);
        sbuf[o * 256 + t] = fmaxf(acc, 0.0f);
    }
    float g[64];
#pragma unroll
    for (int cc = 0; cc < 64; ++cc) g[cc] = sbuf[cc * 256 + t];

#pragma clang loop unroll(disable)
    for (int o = 0; o < 64; ++o) {
        float acc = b1[o];
#pragma unroll
        for (int cc = 0; cc < 64; ++cc) acc = fmaf(w1[o * 64 + cc], g[cc], acc);
        sbuf[o * 256 + t] = fmaxf(acc, 0.0f);
    }
    float h2[64];
#pragma unroll
    for (int cc = 0; cc < 64; ++cc) h2[cc] = sbuf[cc * 256 + t];

#pragma clang loop unroll(disable)
    for (int o = 0; o < 128; ++o) {
        float acc = b2[o];
#pragma unroll
        for (int cc = 0; cc < 64; ++cc) acc = fmaf(w2[o * 64 + cc], h2[cc], acc);
        acc = fmaxf(acc, 0.0f);
#pragma unroll
        for (int m = 16; m >= 1; m >>= 1) acc = fmaxf(acc, __shfl_xor(acc, m));
        if (s == 0) out1[((size_t)(b * 128 + o)) * NPOINT + c] = acc;
    }
}

// ---------------------------------------------------------------------------
extern "C" void kernel_launch(void* const* d_in, const int* in_sizes, int n_in,
                              void* d_out, int out_size, void* d_ws, size_t ws_size,
                              hipStream_t stream)
{
    (void)in_sizes; (void)n_in; (void)out_size; (void)ws_size;

    const float* xyz      = (const float*)d_in[0];
    const float* features = (const float*)d_in[1];
    const float* w_off0   = (const float*)d_in[2];
    const float* b_off0   = (const float*)d_in[3];
    const float* w_off1   = (const float*)d_in[4];
    const float* b_off1   = (const float*)d_in[5];
    const float* w0       = (const float*)d_in[6];
    const float* b0       = (const float*)d_in[7];
    const float* w1       = (const float*)d_in[8];
    const float* b1       = (const float*)d_in[9];
    const float* w2       = (const float*)d_in[10];
    const float* b2       = (const float*)d_in[11];

    char* ws = (char*)d_ws;
    int*   fps_idx = (int*)(ws);                 // 4096 ints      (16 KB)
    float* mod_xyz = (float*)(ws + 16384);       // 4096*3 floats  (48 KB)
    int*   idx_a   = (int*)(ws + 65536);         // 4096*32 ints   (512 KB)
    int*   idx_g   = (int*)(ws + 589824);        // 4096*32 ints   (512 KB)

    float* out0 = (float*)d_out;                              // (B,1024,3)
    float* out1 = (float*)d_out + (size_t)BATCH * NPOINT * 3; // (B,128,1024)

    hipLaunchKernelGGL(fps_kernel, dim3(BATCH), dim3(FPS_T), 0, stream,
                       xyz, fps_idx);
    hipLaunchKernelGGL(ballq_kernel, dim3(BATCH * NPOINT / 4), dim3(256), 0, stream,
                       xyz, fps_idx, (const float*)nullptr, idx_a);
    hipLaunchKernelGGL(offset_kernel, dim3(BATCH * NPOINT / 8), dim3(256), 0, stream,
                       xyz, features, fps_idx, idx_a, w_off0, b_off0, w_off1, b_off1,
                       out0, mod_xyz);
    hipLaunchKernelGGL(ballq_kernel, dim3(BATCH * NPOINT / 4), dim3(256), 0, stream,
                       xyz, (const int*)nullptr, mod_xyz, idx_g);
    hipLaunchKernelGGL(final_kernel, dim3(BATCH * NPOINT / 8), dim3(256), 0, stream,
                       xyz, features, mod_xyz, idx_g, w0, b0, w1, b1, w2, b2, out1);
}

// Round 11
// 2004.368 us; speedup vs baseline: 1.3539x; 1.0042x over previous
//
#include <hip/hip_runtime.h>

#define BATCH   4
#define NPTS    16384
#define NCH     32
#define NPOINT  1024
#define NSAMPLE 32

#define FPS_T 512
#define FPS_K 32            // NPTS / FPS_T
#define FPS_K2 (FPS_K / 2)  // float2-packed pairs

typedef float v2f __attribute__((ext_vector_type(2)));

// ---------------------------------------------------------------------------
// Kernel 1: farthest point sampling. One block per batch; all 64 float2 state
// values are INDIVIDUALLY NAMED variables (macro-expanded) so no array
// indexing exists -> guaranteed SSA/register-resident (rule: runtime-indexed
// arrays go to scratch; round-5 evidence VGPR=96 < 128-reg state floor says
// the array form was memory-allocated). amdgpu_waves_per_eu(2,2) pins the
// allocator budget at 256 VGPRs (round-5 VGPR=96 matches a ~5-waves/EU
// heuristic target that this attribute overrides). Packed float2 math
// (v_pk_*_f32, IEEE-exact vs scalar, contract off preserves reference add
// order); argmax via packed double {hi=dist_bits, lo=~gidx} + v_max_f64
// (first-occurrence ties); one barrier/iter via parity-buffered LDS; winner
// coords via scalar cache.
// ---------------------------------------------------------------------------
#define FPS_DECL(k) v2f px##k, py##k, pz##k, dd##k;
#define FPS_LOAD(k) {                                                   \
    const float* q0 = base + (size_t)(t + (2 * k + 0) * FPS_T) * 3;     \
    const float* q1 = base + (size_t)(t + (2 * k + 1) * FPS_T) * 3;     \
    px##k = (v2f){q0[0], q1[0]};                                        \
    py##k = (v2f){q0[1], q1[1]};                                        \
    pz##k = (v2f){q0[2], q1[2]};                                        \
    dd##k = (v2f){1e10f, 1e10f}; }
#define FPS_STEP(k) {                                                   \
    v2f dx = px##k - cxv;                                               \
    v2f dy = py##k - cyv;                                               \
    v2f dz = pz##k - czv;                                               \
    v2f dsq = dx * dx + dy * dy;                                        \
    dsq = dsq + dz * dz;                                                \
    v2f mm = __builtin_elementwise_min(dd##k, dsq);                     \
    dd##k = mm;                                                         \
    if (mm.x > bv) { bv = mm.x; bk = 2 * k + 0; }                       \
    if (mm.y > bv) { bv = mm.y; bk = 2 * k + 1; } }

__global__ __launch_bounds__(FPS_T)
__attribute__((amdgpu_waves_per_eu(2, 2)))
void fps_kernel(const float* __restrict__ xyz,
                int* __restrict__ fps_idx)
{
    const int b = blockIdx.x;
    const int t = threadIdx.x;
    const float* base = xyz + (size_t)b * NPTS * 3;

    FPS_DECL(0)  FPS_DECL(1)  FPS_DECL(2)  FPS_DECL(3)
    FPS_DECL(4)  FPS_DECL(5)  FPS_DECL(6)  FPS_DECL(7)
    FPS_DECL(8)  FPS_DECL(9)  FPS_DECL(10) FPS_DECL(11)
    FPS_DECL(12) FPS_DECL(13) FPS_DECL(14) FPS_DECL(15)

    FPS_LOAD(0)  FPS_LOAD(1)  FPS_LOAD(2)  FPS_LOAD(3)
    FPS_LOAD(4)  FPS_LOAD(5)  FPS_LOAD(6)  FPS_LOAD(7)
    FPS_LOAD(8)  FPS_LOAD(9)  FPS_LOAD(10) FPS_LOAD(11)
    FPS_LOAD(12) FPS_LOAD(13) FPS_LOAD(14) FPS_LOAD(15)

    __shared__ double s_red[2][FPS_T / 64];

    if (t == 0) fps_idx[b * NPOINT] = 0;
    float cx = base[0], cy = base[1], cz = base[2];

    for (int it = 1; it < NPOINT; ++it) {
        float bv = -1.0f;
        int   bk = 0;   // winning slot (0..31); ascending slot == ascending
                        // global index for fixed t -> strict '>' keeps first
        {
#pragma clang fp contract(off)
            v2f cxv = (v2f){cx, cx};
            v2f cyv = (v2f){cy, cy};
            v2f czv = (v2f){cz, cz};
            FPS_STEP(0)  FPS_STEP(1)  FPS_STEP(2)  FPS_STEP(3)
            FPS_STEP(4)  FPS_STEP(5)  FPS_STEP(6)  FPS_STEP(7)
            FPS_STEP(8)  FPS_STEP(9)  FPS_STEP(10) FPS_STEP(11)
            FPS_STEP(12) FPS_STEP(13) FPS_STEP(14) FPS_STEP(15)
        }
        int bl = ~(t + (bk << 9));  // ~global_idx  (FPS_T == 512)
        // packed argmax candidate: positive-double bit order == (dist, ~idx)
        double best = __hiloint2double(__float_as_int(bv), bl);
#pragma unroll
        for (int m = 32; m >= 1; m >>= 1)
            best = fmax(best, __shfl_xor(best, m));
        if ((t & 63) == 0) s_red[it & 1][t >> 6] = best;
        __syncthreads();
        const double* r = s_red[it & 1];
        double w = fmax(fmax(fmax(r[0], r[1]), fmax(r[2], r[3])),
                        fmax(fmax(r[4], r[5]), fmax(r[6], r[7])));
        unsigned idx = ~(unsigned)__double2loint(w);
        if (t == 0) fps_idx[b * NPOINT + it] = (int)idx;
        unsigned idxu = __builtin_amdgcn_readfirstlane(idx);
        const float* cp = base + (size_t)idxu * 3;  // uniform -> scalar loads
        cx = cp[0]; cy = cp[1]; cz = cp[2];
    }
}

// ---------------------------------------------------------------------------
// Kernel 2/4: ball query. One wave per center, scan points in index order,
// collect first NSAMPLE within radius, pad with first hit (or 0). Early exit.
// cidx != nullptr -> centers gathered from xyz via cidx; else centers array.
// ---------------------------------------------------------------------------
__global__ __launch_bounds__(256) void ballq_kernel(const float* __restrict__ xyz,
                                                    const int* __restrict__ cidx,
                                                    const float* __restrict__ centers,
                                                    int* __restrict__ out_idx)
{
    const int lane = threadIdx.x & 63;
    const int cid  = blockIdx.x * 4 + (threadIdx.x >> 6);
    const int b    = cid >> 10;
    const float* base = xyz + (size_t)b * NPTS * 3;

    float cx, cy, cz;
    if (cidx) {
        int pi = cidx[cid];
        const float* p = base + (size_t)pi * 3;
        cx = p[0]; cy = p[1]; cz = p[2];
    } else {
        const float* p = centers + (size_t)cid * 3;
        cx = p[0]; cy = p[1]; cz = p[2];
    }

    const float R2 = (float)(0.8 * 0.8);
    int found = 0, firstp = 0;
    int* dst = out_idx + (size_t)cid * NSAMPLE;

    for (int chunk = 0; chunk < NPTS / 64; ++chunk) {
        int p = chunk * 64 + lane;
        const float* q = base + (size_t)p * 3;
        bool hit;
        {
#pragma clang fp contract(off)
            float dx = cx - q[0];
            float dy = cy - q[1];
            float dz = cz - q[2];
            float d2 = dx * dx + dy * dy;
            d2 = d2 + dz * dz;
            hit = d2 < R2;
        }
        unsigned long long m = __ballot(hit);
        if (m) {
            if (found == 0) firstp = chunk * 64 + __builtin_ctzll(m);
            int pos = found + __popcll(m & ((1ull << lane) - 1ull));
            if (hit && pos < NSAMPLE) dst[pos] = p;
            found += __popcll(m);
            if (found >= NSAMPLE) break;
        }
    }
    if (found < NSAMPLE) {
        int pad = (found == 0) ? 0 : firstp;
        int j = found + lane;
        if (j < NSAMPLE) dst[j] = pad;
    }
}

// ---------------------------------------------------------------------------
// Kernel 3: grouping + offset MLP (16ch -> 3ch) + mean(st*gxyz) -> mod_xyz,
// clipped copy -> output 0. Thread = (center, sample).
// ---------------------------------------------------------------------------
__global__ __launch_bounds__(256) void offset_kernel(const float* __restrict__ xyz,
                                                     const float* __restrict__ features,
                                                     const int* __restrict__ fps_idx,
                                                     const int* __restrict__ idx_a,
                                                     const float* __restrict__ w0,
                                                     const float* __restrict__ b0,
                                                     const float* __restrict__ w1,
                                                     const float* __restrict__ b1,
                                                     float* __restrict__ out0,
                                                     float* __restrict__ mod_xyz)
{
    const int t   = threadIdx.x;
    const int s   = t & 31;
    const int cid = blockIdx.x * 8 + (t >> 5);
    const int b   = cid >> 10;
    const float* base = xyz + (size_t)b * NPTS * 3;

    int pc = fps_idx[cid];
    const float* cp = base + (size_t)pc * 3;
    float nx = cp[0], ny = cp[1], nz = cp[2];

    int id = idx_a[(size_t)cid * NSAMPLE + s];
    const float* pp = base + (size_t)id * 3;

    float in[3 + NCH];
    in[0] = pp[0] - nx; in[1] = pp[1] - ny; in[2] = pp[2] - nz;
    const float4* fp = reinterpret_cast<const float4*>(features + ((size_t)b * NPTS + id) * NCH);
#pragma unroll
    for (int j = 0; j < NCH / 4; ++j) {
        float4 v = fp[j];
        in[3 + j * 4 + 0] = v.x; in[3 + j * 4 + 1] = v.y;
        in[3 + j * 4 + 2] = v.z; in[3 + j * 4 + 3] = v.w;
    }

    float h[16];
#pragma unroll
    for (int o = 0; o < 16; ++o) {
        float acc = b0[o];
#pragma unroll
        for (int c = 0; c < 35; ++c) acc = fmaf(w0[o * 35 + c], in[c], acc);
        h[o] = fmaxf(acc, 0.0f);
    }
    float st[3];
#pragma unroll
    for (int o = 0; o < 3; ++o) {
        float acc = b1[o];
#pragma unroll
        for (int c = 0; c < 16; ++c) acc = fmaf(w1[o * 16 + c], h[c], acc);
        st[o] = acc;
    }

    float sx = st[0] * in[0];
    float sy = st[1] * in[1];
    float sz = st[2] * in[2];
#pragma unroll
    for (int m = 16; m >= 1; m >>= 1) {
        sx += __shfl_xor(sx, m);
        sy += __shfl_xor(sy, m);
        sz += __shfl_xor(sz, m);
    }
    if (s == 0) {
        float mx = nx + sx * (1.0f / 32.0f);
        float my = ny + sy * (1.0f / 32.0f);
        float mz = nz + sz * (1.0f / 32.0f);
        mod_xyz[cid * 3 + 0] = mx;
        mod_xyz[cid * 3 + 1] = my;
        mod_xyz[cid * 3 + 2] = mz;
        out0[cid * 3 + 0] = fminf(fmaxf(mx, -2.0f), 2.0f);
        out0[cid * 3 + 1] = fminf(fmaxf(my, -2.0f), 2.0f);
        out0[cid * 3 + 2] = fminf(fmaxf(mz, -2.0f), 2.0f);
    }
}

// ---------------------------------------------------------------------------
// Kernel 5: grouping (mod_xyz, idx_g) + MLP 35->64->64->128 + max over samples.
// Output-channel loops stay rolled (uniform weight rows -> s_load + v_fmac);
// activations round-trip through per-thread LDS columns (conflict-free) so no
// runtime-indexed register arrays (which would spill to scratch).
// ---------------------------------------------------------------------------
__global__ __launch_bounds__(256) void final_kernel(const float* __restrict__ xyz,
                                                    const float* __restrict__ features,
                                                    const float* __restrict__ mod_xyz,
                                                    const int* __restrict__ idx_g,
                                                    const float* __restrict__ w0,
                                                    const float* __restrict__ b0,
                                                    const float* __restrict__ w1,
                                                    const float* __restrict__ b1,
                                                    const float* __restrict__ w2,
                                                    const float* __restrict__ b2,
                                                    float* __restrict__ out1)
{
    __shared__ float sbuf[64 * 256];
    const int t   = threadIdx.x;
    const int s   = t & 31;
    const int cid = blockIdx.x * 8 + (t >> 5);
    const int b   = cid >> 10;
    const int c   = cid & (NPOINT - 1);
    const float* base = xyz + (size_t)b * NPTS * 3;

    float nx = mod_xyz[cid * 3 + 0];
    float ny = mod_xyz[cid * 3 + 1];
    float nz = mod_xyz[cid * 3 + 2];
    int id = idx_g[(size_t)cid * NSAMPLE + s];
    const float* pp = base + (size_t)id * 3;

    float in[35];
    in[0] = pp[0] - nx; in[1] = pp[1] - ny; in[2] = pp[2] - nz;
    const float4* fp = reinterpret_cast<const float4*>(features + ((size_t)b * NPTS + id) * NCH);
#pragma unroll
    for (int j = 0; j < 8; ++j) {
        float4 v = fp[j];
        in[3 + j * 4 + 0] = v.x; in[3 + j * 4 + 1] = v.y;
        in[3 + j * 4 + 2] = v.z; in[3 + j * 4 + 3] = v.w;
    }

#pragma clang loop unroll(disable)
    for (int o = 0; o < 64; ++o) {
        float acc = b0[o];
#pragma unroll
        for (int cc = 0; cc < 35; ++cc) acc = fmaf(w0[o * 35 + cc], in[cc], acc);
        sbuf[o * 256 + t] = fmaxf(acc, 0.0f);
    }
    float g[64];
#pragma unroll
    for (int cc = 0; cc < 64; ++cc) g[cc] = sbuf[cc * 256 + t];

#pragma clang loop unroll(disable)
    for (int o = 0; o < 64; ++o) {
        float acc = b1[o];
#pragma unroll
        for (int cc = 0; cc < 64; ++cc) acc = fmaf(w1[o * 64 + cc], g[cc], acc);
        sbuf[o * 256 + t] = fmaxf(acc, 0.0f);
    }
    float h2[64];
#pragma unroll
    for (int cc = 0; cc < 64; ++cc) h2[cc] = sbuf[cc * 256 + t];

#pragma clang loop unroll(disable)
    for (int o = 0; o < 128; ++o) {
        float acc = b2[o];
#pragma unroll
        for (int cc = 0; cc < 64; ++cc) acc = fmaf(w2[o * 64 + cc], h2[cc], acc);
        acc = fmaxf(acc, 0.0f);
#pragma unroll
        for (int m = 16; m >= 1; m >>= 1) acc = fmaxf(acc, __shfl_xor(acc, m));
        if (s == 0) out1[((size_t)(b * 128 + o)) * NPOINT + c] = acc;
    }
}

// ---------------------------------------------------------------------------
extern "C" void kernel_launch(void* const* d_in, const int* in_sizes, int n_in,
                              void* d_out, int out_size, void* d_ws, size_t ws_size,
                              hipStream_t stream)
{
    (void)in_sizes; (void)n_in; (void)out_size; (void)ws_size;

    const float* xyz      = (const float*)d_in[0];
    const float* features = (const float*)d_in[1];
    const float* w_off0   = (const float*)d_in[2];
    const float* b_off0   = (const float*)d_in[3];
    const float* w_off1   = (const float*)d_in[4];
    const float* b_off1   = (const float*)d_in[5];
    const float* w0       = (const float*)d_in[6];
    const float* b0       = (const float*)d_in[7];
    const float* w1       = (const float*)d_in[8];
    const float* b1       = (const float*)d_in[9];
    const float* w2       = (const float*)d_in[10];
    const float* b2       = (const float*)d_in[11];

    char* ws = (char*)d_ws;
    int*   fps_idx = (int*)(ws);                 // 4096 ints      (16 KB)
    float* mod_xyz = (float*)(ws + 16384);       // 4096*3 floats  (48 KB)
    int*   idx_a   = (int*)(ws + 65536);         // 4096*32 ints   (512 KB)
    int*   idx_g   = (int*)(ws + 589824);        // 4096*32 ints   (512 KB)

    float* out0 = (float*)d_out;                              // (B,1024,3)
    float* out1 = (float*)d_out + (size_t)BATCH * NPOINT * 3; // (B,128,1024)

    hipLaunchKernelGGL(fps_kernel, dim3(BATCH), dim3(FPS_T), 0, stream,
                       xyz, fps_idx);
    hipLaunchKernelGGL(ballq_kernel, dim3(BATCH * NPOINT / 4), dim3(256), 0, stream,
                       xyz, fps_idx, (const float*)nullptr, idx_a);
    hipLaunchKernelGGL(offset_kernel, dim3(BATCH * NPOINT / 8), dim3(256), 0, stream,
                       xyz, features, fps_idx, idx_a, w_off0, b_off0, w_off1, b_off1,
                       out0, mod_xyz);
    hipLaunchKernelGGL(ballq_kernel, dim3(BATCH * NPOINT / 4), dim3(256), 0, stream,
                       xyz, (const int*)nullptr, mod_xyz, idx_g);
    hipLaunchKernelGGL(final_kernel, dim3(BATCH * NPOINT / 8), dim3(256), 0, stream,
                       xyz, features, mod_xyz, idx_g, w0, b0, w1, b1, w2, b2, out1);
}